// Round 13
// baseline (2414.266 us; speedup 1.0000x reference)
//
#include <hip/hip_runtime.h>
#include <hip/hip_fp16.h>

// LSTM: B=128, T=1024, I=1, H=512, O=1
// R13 = R12 (16 WGs/bg x 32 units, tag-in-payload, DPP transpose, hist
// readout) + XCD-local shadow exchange, FIXED fallback policy:
//  - producers dual-publish tagged shorts: sc0 -> shadow (bg's XCD L2 under
//    round-robin dispatch) AND sc0 sc1 -> canonical (LLC, liveness).
//  - consumers poll shadow (sc0); every 8th retry polls canonical (sc0 sc1).
//    Non-sticky: no warmup-poisoned permanent fallback (R10's bug).

typedef _Float16 f16;
typedef _Float16 f16x8 __attribute__((ext_vector_type(8)));
typedef float f32x4 __attribute__((ext_vector_type(4)));

#define BATCH 128
#define TT 1024
#define HID 512

#define WPACK_OFF   0
#define WPACK_BYTES (16*4*2*16*64*16)            // 2 MiB packed f16 Wh fragments
#define HBUF_OFF    WPACK_BYTES
#define HBUF_ELEMS  (BATCH*HID)                  // 65536 f16 = 128 KiB per buffer
#define SHBUF_OFF   (HBUF_OFF + 4*HBUF_ELEMS*2)  // shadow: 4 more buffers
#define WL16_OFF    (SHBUF_OFF + 4*HBUF_ELEMS*2)
#define HHIST_OFF   (WL16_OFF + 4096)
#define HHIST_BYTES ((size_t)TT * BATCH * HID * 2)   // 128 MiB
#define WS_NEEDED   ((size_t)HHIST_OFF + HHIST_BYTES)

__global__ __launch_bounds__(256) void init_kernel(const float* Wl, f16* wl16,
                                                   unsigned* hbuf, unsigned* hsh) {
    int idx = blockIdx.x * 256 + threadIdx.x;    // grid 512*256 = 131072
    // buf0 = zeros (h_0, tag 0); bufs 1..3 = 0x00010001 (both halves stale)
    unsigned v = ((idx >> 15) == 0) ? 0u : 0x00010001u;
    hbuf[idx] = v;
    hsh[idx]  = v;
    if (idx < HID) wl16[idx] = (f16)Wl[idx];
}

// Pack Wh (512 x 2048, row = source k, col = gate*512 + j) into per-(cg,wv,T)
// B-fragments. cg 0..15 owns units cg*32..cg*32+31; tile T in {0,1} covers
// units cg*32 + T*16 + wv*4 + jj. Slot s = physical k-tile jt=(wv*4+s)&15.
__global__ __launch_bounds__(256) void pack_kernel(const float* __restrict__ Wh,
                                                   f16* __restrict__ wpack) {
    int tid  = blockIdx.x * 256 + threadIdx.x;   // 131072 = 16cg*4wv*2T*16s*64l
    int lane = tid & 63;
    int s    = (tid >> 6) & 15;
    int T    = (tid >> 10) & 1;
    int wv   = (tid >> 11) & 3;
    int cg   = tid >> 13;                        // 0..15
    int l_lo = lane & 15, l_hi = lane >> 4;
    int jt = ((wv * 4) + s) & 15;                // physical k-tile
    int jj = l_lo >> 2, q = l_lo & 3;
    int c = q * 512 + cg * 32 + T * 16 + wv * 4 + jj;
    int kbase = jt * 32 + l_hi * 8;
    f16x8 v;
#pragma unroll
    for (int e = 0; e < 8; ++e) v[e] = (f16)Wh[(kbase + e) * 2048 + c];
    ((f16x8*)wpack)[tid] = v;
}

__device__ __forceinline__ float dot8(f16x8 a, f16x8 b, float acc) {
#if __has_builtin(__builtin_amdgcn_fdot2)
    acc = __builtin_amdgcn_fdot2(__builtin_shufflevector(a, a, 0, 1),
                                 __builtin_shufflevector(b, b, 0, 1), acc, false);
    acc = __builtin_amdgcn_fdot2(__builtin_shufflevector(a, a, 2, 3),
                                 __builtin_shufflevector(b, b, 2, 3), acc, false);
    acc = __builtin_amdgcn_fdot2(__builtin_shufflevector(a, a, 4, 5),
                                 __builtin_shufflevector(b, b, 4, 5), acc, false);
    acc = __builtin_amdgcn_fdot2(__builtin_shufflevector(a, a, 6, 7),
                                 __builtin_shufflevector(b, b, 6, 7), acc, false);
#else
#pragma unroll
    for (int e = 0; e < 8; ++e) acc += (float)a[e] * (float)b[e];
#endif
    return acc;
}

// quad_perm DPP: xor1 = 0xB1, xor2 = 0x4E (quad-local strides 1/2).
template<int CTRL>
__device__ __forceinline__ float dpp_qp(float v) {
    int r = __builtin_amdgcn_update_dpp(0, __builtin_bit_cast(int, v),
                                        CTRL, 0xF, 0xF, true);
    return __builtin_bit_cast(float, r);
}

// 4x4 transpose within aligned lane quads: m[0..3] -> (f0..f3) per p4.
__device__ __forceinline__ void quad_transpose(const f32x4& m, int p4,
                                               float& f0, float& f1,
                                               float& f2, float& f3) {
    float t0, e0, e1, e2, e3;
    t0 = dpp_qp<0xB1>(m[1]); e0 = (p4 & 1) ? t0 : m[0];
    t0 = dpp_qp<0xB1>(m[0]); e1 = (p4 & 1) ? m[1] : t0;
    t0 = dpp_qp<0xB1>(m[3]); e2 = (p4 & 1) ? t0 : m[2];
    t0 = dpp_qp<0xB1>(m[2]); e3 = (p4 & 1) ? m[3] : t0;
    t0 = dpp_qp<0x4E>(e2); f0 = (p4 & 2) ? t0 : e0;
    t0 = dpp_qp<0x4E>(e3); f1 = (p4 & 2) ? t0 : e1;
    t0 = dpp_qp<0x4E>(e0); f2 = (p4 & 2) ? e2 : t0;
    t0 = dpp_qp<0x4E>(e1); f3 = (p4 & 2) ? e3 : t0;
}

// MODE 0: hist readout (separate kernel). MODE 1: in-kernel readout fallback.
template<int MODE>
__global__ __launch_bounds__(256, 1) void lstm_kernel(
    const float* __restrict__ x, const float* __restrict__ Wx,
    const float* __restrict__ bvec, const float* __restrict__ blp,
    const f16* __restrict__ wpack, f16* __restrict__ hbuf,
    f16* __restrict__ hshadow, const f16* __restrict__ wl16,
    f16* __restrict__ hhist, float* __restrict__ out)
{
    const int tid = threadIdx.x;
    const int cg = blockIdx.x >> 3;      // hidden-group 0..15 (32 units each)
    const int bg = blockIdx.x & 7;       // batch-group 0..7 (== XCD, round-robin)
    const int w = tid >> 6, lane = tid & 63;
    const int l_lo = lane & 15, l_hi = lane >> 4;

    __shared__ f16 hsh[2][8192];         // [row16][k512], XOR-swizzled, dbuf
    __shared__ f16 wlsh[512];

    if (tid < 64)                         // Wl -> LDS once (fallback readout)
        *(f16x8*)(wlsh + tid * 8) = *(const f16x8*)(wl16 + tid * 8);

    // ---- persistent B fragments: two 16-col tiles, slot s = jt=(w*4+s)&15 ----
    f16x8 bf0[16], bf1[16];
    {
        const f16x8* wp0 = (const f16x8*)wpack
                         + (size_t)(((cg * 4 + w) * 2 + 0) * 16) * 64 + lane;
        const f16x8* wp1 = (const f16x8*)wpack
                         + (size_t)(((cg * 4 + w) * 2 + 1) * 16) * 64 + lane;
#pragma unroll
        for (int s = 0; s < 16; ++s) { bf0[s] = wp0[s * 64]; bf1[s] = wp1[s * 64]; }
    }

    // ---- per-lane (row, unit) ownership after transpose ----
    const int row  = l_hi * 4 + (l_lo & 3);
    const int u0 = cg * 32 + w * 4 + (l_lo >> 2);      // tile0 unit
    const int u1 = u0 + 16;                            // tile1 unit
    const int bglob = bg * 16 + row;
    const float bi0 = bvec[0*512+u0], bfo0 = bvec[1*512+u0];
    const float bg0 = bvec[2*512+u0], bo0 = bvec[3*512+u0];
    const float bi1 = bvec[0*512+u1], bfo1 = bvec[1*512+u1];
    const float bg1 = bvec[2*512+u1], bo1 = bvec[3*512+u1];
    const float wxi0 = Wx[0*512+u0], wxf0 = Wx[1*512+u0];
    const float wxg0 = Wx[2*512+u0], wxo0 = Wx[3*512+u0];
    const float wxi1 = Wx[0*512+u1], wxf1 = Wx[1*512+u1];
    const float wxg1 = Wx[2*512+u1], wxo1 = Wx[3*512+u1];
    const float blv = blp[0];

    // poll: lane covers row l_lo, k in wave w's quarter (layout unchanged)
    const int rd_base = bg * 8192 + ((w * 16 + l_hi) * 16 + l_lo) * 8;
    // publish: f16 slot [kblock=u>>3][row][u&7], per tile
    const int st_idx0 = bg * 8192 + ((u0 >> 3) * 16 + row) * 8 + (u0 & 7);
    const int st_idx1 = bg * 8192 + ((u1 >> 3) * 16 + row) * 8 + (u1 & 7);
    // hist layout [t][b][u]
    const int hist0 = (bg * 16 + row) * 512 + u0;
    const int hist1 = (bg * 16 + row) * 512 + u1;

    const int p4 = l_lo & 3;             // in-group transpose id
    const int sx = (l_lo & 7) << 4;      // LDS XOR swizzle
    const int lbase = l_lo * 1024;       // LDS row byte base
    const int base_ws = w * 256 + l_hi * 16;  // in-row byte off of slot 0
    const int xrow = bglob * TT;

    float cst0 = 0.f, cst1 = 0.f;
    const int TLAST = (MODE == 0) ? (TT - 1) : TT;

    for (int t = 0; t <= TLAST; ++t) {
        const f16* hp  = hbuf    + (size_t)(t & 3) * HBUF_ELEMS + rd_base;
        const f16* hpS = hshadow + (size_t)(t & 3) * HBUF_ELEMS + rd_base;
        const unsigned ep = (unsigned)((t >> 2) & 1) * 0x00010001u;
        float xv = x[xrow + (t < TT ? t : 0)];   // hoisted; arrives under poll

        // ---- hybrid poll: shadow (sc0, XCD L2); every 8th retry -> LLC ----
        f16x8 s0, s1, s2, s3;
        unsigned r = 0;
        for (;;) {
            if ((r++ & 7) != 7) {
                asm volatile(
                    "global_load_dwordx4 %0, %4, off sc0\n\t"
                    "global_load_dwordx4 %1, %5, off sc0\n\t"
                    "global_load_dwordx4 %2, %6, off sc0\n\t"
                    "global_load_dwordx4 %3, %7, off sc0\n\t"
                    "s_waitcnt vmcnt(0)"
                    : "=&v"(s0), "=&v"(s1), "=&v"(s2), "=&v"(s3)
                    : "v"(hpS), "v"(hpS + 512), "v"(hpS + 1024), "v"(hpS + 1536)
                    : "memory");
            } else {
                asm volatile(
                    "global_load_dwordx4 %0, %4, off sc0 sc1\n\t"
                    "global_load_dwordx4 %1, %5, off sc0 sc1\n\t"
                    "global_load_dwordx4 %2, %6, off sc0 sc1\n\t"
                    "global_load_dwordx4 %3, %7, off sc0 sc1\n\t"
                    "s_waitcnt vmcnt(0)"
                    : "=&v"(s0), "=&v"(s1), "=&v"(s2), "=&v"(s3)
                    : "v"(hp), "v"(hp + 512), "v"(hp + 1024), "v"(hp + 1536)
                    : "memory");
            }
            union { f16x8 v; unsigned u[4]; } b0, b1, b2, b3;
            b0.v = s0; b1.v = s1; b2.v = s2; b3.v = s3;
            unsigned bad =
                (((b0.u[0]^ep)|(b0.u[1]^ep)|(b0.u[2]^ep)|(b0.u[3]^ep)) |
                 ((b1.u[0]^ep)|(b1.u[1]^ep)|(b1.u[2]^ep)|(b1.u[3]^ep)) |
                 ((b2.u[0]^ep)|(b2.u[1]^ep)|(b2.u[2]^ep)|(b2.u[3]^ep)) |
                 ((b3.u[0]^ep)|(b3.u[1]^ep)|(b3.u[2]^ep)|(b3.u[3]^ep))) & 0x00010001u;
            if (__all(bad == 0u)) break;
        }
        __builtin_amdgcn_sched_barrier(0);

        // ---- stage wave's k-quarter into shared h tile (swizzled) ----
        char* hb = (char*)hsh[t & 1];
        const int wb = lbase + base_ws;
        *(f16x8*)(hb + ((wb +   0) ^ sx)) = s0;
        *(f16x8*)(hb + ((wb +  64) ^ sx)) = s1;
        *(f16x8*)(hb + ((wb + 128) ^ sx)) = s2;
        *(f16x8*)(hb + ((wb + 192) ^ sx)) = s3;

        // ---- own-quarter MFMA chains BEFORE the barrier (both tiles) ----
        f32x4 cA0 = {0,0,0,0}, cA1 = {0,0,0,0};
        if (t < TT) {
            cA0 = __builtin_amdgcn_mfma_f32_16x16x32_f16(s0, bf0[0], cA0, 0,0,0);
            cA1 = __builtin_amdgcn_mfma_f32_16x16x32_f16(s0, bf1[0], cA1, 0,0,0);
            cA0 = __builtin_amdgcn_mfma_f32_16x16x32_f16(s1, bf0[1], cA0, 0,0,0);
            cA1 = __builtin_amdgcn_mfma_f32_16x16x32_f16(s1, bf1[1], cA1, 0,0,0);
            cA0 = __builtin_amdgcn_mfma_f32_16x16x32_f16(s2, bf0[2], cA0, 0,0,0);
            cA1 = __builtin_amdgcn_mfma_f32_16x16x32_f16(s2, bf1[2], cA1, 0,0,0);
            cA0 = __builtin_amdgcn_mfma_f32_16x16x32_f16(s3, bf0[3], cA0, 0,0,0);
            cA1 = __builtin_amdgcn_mfma_f32_16x16x32_f16(s3, bf1[3], cA1, 0,0,0);
        }
        __syncthreads();

        if (t < TT) {
            // ---- remaining 12 slots from LDS (read once, 2 MFMAs each) ----
            f32x4 cB0 = {0,0,0,0}, cB1 = {0,0,0,0};
            f32x4 cC0 = {0,0,0,0}, cC1 = {0,0,0,0};
            f32x4 cD0 = {0,0,0,0}, cD1 = {0,0,0,0};
#pragma unroll
            for (int i = 0; i < 4; ++i) {
                f16x8 a1 = *(const f16x8*)(hb + ((lbase + ((base_ws + (4+i)*64) & 1023)) ^ sx));
                f16x8 a2 = *(const f16x8*)(hb + ((lbase + ((base_ws + (8+i)*64) & 1023)) ^ sx));
                f16x8 a3 = *(const f16x8*)(hb + ((lbase + ((base_ws + (12+i)*64) & 1023)) ^ sx));
                cB0 = __builtin_amdgcn_mfma_f32_16x16x32_f16(a1, bf0[ 4+i], cB0, 0,0,0);
                cB1 = __builtin_amdgcn_mfma_f32_16x16x32_f16(a1, bf1[ 4+i], cB1, 0,0,0);
                cC0 = __builtin_amdgcn_mfma_f32_16x16x32_f16(a2, bf0[ 8+i], cC0, 0,0,0);
                cC1 = __builtin_amdgcn_mfma_f32_16x16x32_f16(a2, bf1[ 8+i], cC1, 0,0,0);
                cD0 = __builtin_amdgcn_mfma_f32_16x16x32_f16(a3, bf0[12+i], cD0, 0,0,0);
                cD1 = __builtin_amdgcn_mfma_f32_16x16x32_f16(a3, bf1[12+i], cD1, 0,0,0);
            }
            f32x4 m0 = (cA0 + cB0) + (cC0 + cD0);
            f32x4 m1 = (cA1 + cB1) + (cC1 + cD1);

            // ---- transpose + activations, two independent chains (ILP) ----
            float gi0, gf0, gg0, go0, gi1, gf1, gg1, go1;
            quad_transpose(m0, p4, gi0, gf0, gg0, go0);
            quad_transpose(m1, p4, gi1, gf1, gg1, go1);

            gi0 += xv * wxi0 + bi0;  gf0 += xv * wxf0 + bfo0;
            gg0 += xv * wxg0 + bg0;  go0 += xv * wxo0 + bo0;
            gi1 += xv * wxi1 + bi1;  gf1 += xv * wxf1 + bfo1;
            gg1 += xv * wxg1 + bg1;  go1 += xv * wxo1 + bo1;

            float iv0 = 1.f / (1.f + __expf(-gi0));
            float fv0 = 1.f / (1.f + __expf(-gf0));
            float gv0 = 2.f / (1.f + __expf(-2.f * gg0)) - 1.f;
            float ov0 = 1.f / (1.f + __expf(-go0));
            float iv1 = 1.f / (1.f + __expf(-gi1));
            float fv1 = 1.f / (1.f + __expf(-gf1));
            float gv1 = 2.f / (1.f + __expf(-2.f * gg1)) - 1.f;
            float ov1 = 1.f / (1.f + __expf(-go1));
            cst0 = fv0 * cst0 + iv0 * gv0;
            cst1 = fv1 * cst1 + iv1 * gv1;
            float hv0 = ov0 * (2.f / (1.f + __expf(-2.f * cst0)) - 1.f);
            float hv1 = ov1 * (2.f / (1.f + __expf(-2.f * cst1)) - 1.f);

            unsigned h0, h1;
            { union { f16 f; unsigned short s; } cv;
              cv.f = (f16)hv0; h0 = cv.s; cv.f = (f16)hv1; h1 = cv.s; }

            // ---- dual publish: shadow (sc0) first, then canonical (LLC) ----
            if ((MODE == 0) ? (t < TT - 1) : true) {
                const unsigned wtag = (unsigned)(((t + 1) >> 2) & 1);
                unsigned tg0 = (h0 & 0xFFFEu) | wtag;
                unsigned tg1 = (h1 & 0xFFFEu) | wtag;
                size_t boff = (size_t)((t + 1) & 3) * HBUF_ELEMS;
                f16* dstb = hbuf + boff;
                f16* dstS = hshadow + boff;
                asm volatile("global_store_short %0, %1, off sc0"
                             :: "v"(dstS + st_idx0), "v"(tg0) : "memory");
                asm volatile("global_store_short %0, %1, off sc0"
                             :: "v"(dstS + st_idx1), "v"(tg1) : "memory");
                asm volatile("global_store_short %0, %1, off sc0 sc1"
                             :: "v"(dstb + st_idx0), "v"(tg0) : "memory");
                asm volatile("global_store_short %0, %1, off sc0 sc1"
                             :: "v"(dstb + st_idx1), "v"(tg1) : "memory");
            }

            // ---- hist side-store (pre-tag precision), plain cached ----
            if (MODE == 0) {
                f16* hd = hhist + (size_t)t * (BATCH * HID);
                asm volatile("global_store_short %0, %1, off"
                             :: "v"(hd + hist0), "v"(h0) : "memory");
                asm volatile("global_store_short %0, %1, off"
                             :: "v"(hd + hist1), "v"(h1) : "memory");
            }
        }

        // ---- fallback in-kernel readout, rotates over (cg,w) ----
        if (MODE == 1 && t >= 1 && cg == ((t >> 2) & 15) && w == (t & 3)) {
            float r0 = 0.f, r1 = 0.f, r2 = 0.f, r3 = 0.f;
#define WL(s) (*(const f16x8*)(wlsh + (((base_ws + (s)*64) & 1023) >> 1)))
            r0 = dot8(s0, WL(0), r0);
            r1 = dot8(s1, WL(1), r1);
            r2 = dot8(s2, WL(2), r2);
            r3 = dot8(s3, WL(3), r3);
#pragma unroll
            for (int i = 0; i < 4; ++i) {
                f16x8 a1 = *(const f16x8*)(hb + ((lbase + ((base_ws + (4+i)*64) & 1023)) ^ sx));
                f16x8 a2 = *(const f16x8*)(hb + ((lbase + ((base_ws + (8+i)*64) & 1023)) ^ sx));
                f16x8 a3 = *(const f16x8*)(hb + ((lbase + ((base_ws + (12+i)*64) & 1023)) ^ sx));
                r0 = dot8(a1, WL(4+i),  r0);
                r1 = dot8(a2, WL(8+i),  r1);
                r2 = dot8(a3, WL(12+i), r2);
            }
#undef WL
            float ry = (r0 + r1) + (r2 + r3);
            ry += __shfl_xor(ry, 16);
            ry += __shfl_xor(ry, 32);
            if (lane < 16)
                out[(bg * 16 + l_lo) * TT + (t - 1)] = blv + ry;
        }
    }
}

// y[b][t] = sum_u hhist[t][b][u] * Wl[u] + bl. One wave per (b, 8 t's).
__global__ __launch_bounds__(256) void readout_kernel(
    const f16* __restrict__ hhist, const float* __restrict__ Wl,
    const float* __restrict__ blp, float* __restrict__ out)
{
    int gw = (blockIdx.x * 256 + threadIdx.x) >> 6;   // 0..16383
    int lane = threadIdx.x & 63;
    int b = gw >> 7;
    int t0 = (gw & 127) * 8;
    const float4* wp = (const float4*)(Wl + lane * 8);
    float4 wa = wp[0], wb = wp[1];
    float blv = blp[0];
    const f16* hp = hhist + (size_t)t0 * (BATCH * HID) + b * HID + lane * 8;
#pragma unroll
    for (int j = 0; j < 8; ++j) {
        f16x8 h8 = *(const f16x8*)(hp + (size_t)j * (BATCH * HID));
        float p = (float)h8[0]*wa.x + (float)h8[1]*wa.y + (float)h8[2]*wa.z +
                  (float)h8[3]*wa.w + (float)h8[4]*wb.x + (float)h8[5]*wb.y +
                  (float)h8[6]*wb.z + (float)h8[7]*wb.w;
        p += __shfl_xor(p, 1);  p += __shfl_xor(p, 2);  p += __shfl_xor(p, 4);
        p += __shfl_xor(p, 8);  p += __shfl_xor(p, 16); p += __shfl_xor(p, 32);
        if (lane == 0) out[b * TT + t0 + j] = p + blv;
    }
}

extern "C" void kernel_launch(void* const* d_in, const int* in_sizes, int n_in,
                              void* d_out, int out_size, void* d_ws, size_t ws_size,
                              hipStream_t stream) {
    const float* x  = (const float*)d_in[0];
    const float* Wx = (const float*)d_in[1];
    const float* Wh = (const float*)d_in[2];
    const float* bv = (const float*)d_in[3];
    const float* Wl = (const float*)d_in[4];
    const float* bl = (const float*)d_in[5];
    float* out = (float*)d_out;
    char* ws = (char*)d_ws;

    f16* wpack   = (f16*)(ws + WPACK_OFF);
    f16* hbuf    = (f16*)(ws + HBUF_OFF);
    f16* hshadow = (f16*)(ws + SHBUF_OFF);
    f16* wl16    = (f16*)(ws + WL16_OFF);
    f16* hhist   = (f16*)(ws + HHIST_OFF);

    init_kernel<<<512, 256, 0, stream>>>(Wl, wl16, (unsigned*)hbuf,
                                         (unsigned*)hshadow);
    pack_kernel<<<512, 256, 0, stream>>>(Wh, wpack);
    if (ws_size >= WS_NEEDED) {
        lstm_kernel<0><<<128, 256, 0, stream>>>(x, Wx, bv, bl, wpack, hbuf,
                                                hshadow, wl16, hhist, out);
        readout_kernel<<<4096, 256, 0, stream>>>(hhist, Wl, bl, out);
    } else {
        lstm_kernel<1><<<128, 256, 0, stream>>>(x, Wx, bv, bl, wpack, hbuf,
                                                hshadow, wl16, hhist, out);
    }
}

// Round 14
// 1794.184 us; speedup vs baseline: 1.3456x; 1.3456x over previous
//
#include <hip/hip_runtime.h>
#include <hip/hip_fp16.h>

// LSTM: B=128, T=1024, I=1, H=512, O=1
// R14 = R12 (best structure) + fully-coalesced publish:
//  - wave owns units [cg*32+w*8, +8) = exactly ONE kblock (cg*4+w) per bg.
//  - in-kblock k-permutation perm[e]=(e>>1)|((e&1)<<2) applied to BOTH the
//    Wh B-pack and Wl (A/B k-order cancels), so each lane packs (h0,h1) into
//    one dword; 3 shfl_xor gather 4 dwords/row; 16 writer lanes store ONE
//    coalesced 256B dwordx4 burst per wave per step (was 128 scattered 2B).
//  - hist side-store reuses the same packed regs (tag bit = <=1ulp noise).

typedef _Float16 f16;
typedef _Float16 f16x8 __attribute__((ext_vector_type(8)));
typedef float f32x4 __attribute__((ext_vector_type(4)));

#define BATCH 128
#define TT 1024
#define HID 512

#define WPACK_OFF   0
#define WPACK_BYTES (16*4*2*16*64*16)            // 2 MiB packed f16 Wh fragments
#define HBUF_OFF    WPACK_BYTES
#define HBUF_ELEMS  (BATCH*HID)                  // 65536 f16 = 128 KiB per buffer
#define WL16_OFF    (HBUF_OFF + 4*HBUF_ELEMS*2)
#define WLP_OFF     (WL16_OFF + 1024)            // permuted float Wl (2 KB)
#define HHIST_OFF   (WL16_OFF + 4096)
#define HHIST_BYTES ((size_t)TT * BATCH * HID * 2)   // 128 MiB
#define WS_NEEDED   ((size_t)HHIST_OFF + HHIST_BYTES)

__device__ __host__ __forceinline__ int kperm(int e) {
    return (e >> 1) | ((e & 1) << 2);            // [0,4,1,5,2,6,3,7]
}

__global__ __launch_bounds__(256) void init_kernel(const float* Wl, f16* wl16,
                                                   float* wlp, unsigned* hbuf) {
    int idx = blockIdx.x * 256 + threadIdx.x;    // grid 512*256 = 131072
    // buf0 = zeros (h_0, tag 0); bufs 1..3 = 0x00010001 (both halves stale)
    hbuf[idx] = ((idx >> 15) == 0) ? 0u : 0x00010001u;
    if (idx < HID) {                             // permuted Wl copies
        int kb = idx >> 3, e = idx & 7;
        float v = Wl[kb * 8 + kperm(e)];
        wl16[idx] = (f16)v;
        wlp[idx] = v;
    }
}

// Pack Wh (512 x 2048, row = source k, col = gate*512 + j) into per-(cg,wv,T)
// B-fragments. Wave wv of cg owns units cg*32 + wv*8 .. +8; tile T covers
// units cg*32 + wv*8 + T*4 + jj. Slot s = physical k-tile jt=(wv*4+s)&15.
// k rows inside each kblock are permuted by kperm (matches publish layout).
__global__ __launch_bounds__(256) void pack_kernel(const float* __restrict__ Wh,
                                                   f16* __restrict__ wpack) {
    int tid  = blockIdx.x * 256 + threadIdx.x;   // 131072 = 16cg*4wv*2T*16s*64l
    int lane = tid & 63;
    int s    = (tid >> 6) & 15;
    int T    = (tid >> 10) & 1;
    int wv   = (tid >> 11) & 3;
    int cg   = tid >> 13;                        // 0..15
    int l_lo = lane & 15, l_hi = lane >> 4;
    int jt = ((wv * 4) + s) & 15;                // physical k-tile
    int jj = l_lo >> 2, q = l_lo & 3;
    int c = q * 512 + cg * 32 + wv * 8 + T * 4 + jj;
    int kbase = jt * 32 + l_hi * 8;
    f16x8 v;
#pragma unroll
    for (int e = 0; e < 8; ++e) v[e] = (f16)Wh[(kbase + kperm(e)) * 2048 + c];
    ((f16x8*)wpack)[tid] = v;
}

__device__ __forceinline__ float dot8(f16x8 a, f16x8 b, float acc) {
#if __has_builtin(__builtin_amdgcn_fdot2)
    acc = __builtin_amdgcn_fdot2(__builtin_shufflevector(a, a, 0, 1),
                                 __builtin_shufflevector(b, b, 0, 1), acc, false);
    acc = __builtin_amdgcn_fdot2(__builtin_shufflevector(a, a, 2, 3),
                                 __builtin_shufflevector(b, b, 2, 3), acc, false);
    acc = __builtin_amdgcn_fdot2(__builtin_shufflevector(a, a, 4, 5),
                                 __builtin_shufflevector(b, b, 4, 5), acc, false);
    acc = __builtin_amdgcn_fdot2(__builtin_shufflevector(a, a, 6, 7),
                                 __builtin_shufflevector(b, b, 6, 7), acc, false);
#else
#pragma unroll
    for (int e = 0; e < 8; ++e) acc += (float)a[e] * (float)b[e];
#endif
    return acc;
}

// quad_perm DPP: xor1 = 0xB1, xor2 = 0x4E (quad-local strides 1/2).
template<int CTRL>
__device__ __forceinline__ float dpp_qp(float v) {
    int r = __builtin_amdgcn_update_dpp(0, __builtin_bit_cast(int, v),
                                        CTRL, 0xF, 0xF, true);
    return __builtin_bit_cast(float, r);
}

// 4x4 transpose within aligned lane quads: m[0..3] -> (f0..f3) per p4.
__device__ __forceinline__ void quad_transpose(const f32x4& m, int p4,
                                               float& f0, float& f1,
                                               float& f2, float& f3) {
    float t0, e0, e1, e2, e3;
    t0 = dpp_qp<0xB1>(m[1]); e0 = (p4 & 1) ? t0 : m[0];
    t0 = dpp_qp<0xB1>(m[0]); e1 = (p4 & 1) ? m[1] : t0;
    t0 = dpp_qp<0xB1>(m[3]); e2 = (p4 & 1) ? t0 : m[2];
    t0 = dpp_qp<0xB1>(m[2]); e3 = (p4 & 1) ? m[3] : t0;
    t0 = dpp_qp<0x4E>(e2); f0 = (p4 & 2) ? t0 : e0;
    t0 = dpp_qp<0x4E>(e3); f1 = (p4 & 2) ? t0 : e1;
    t0 = dpp_qp<0x4E>(e0); f2 = (p4 & 2) ? e2 : t0;
    t0 = dpp_qp<0x4E>(e1); f3 = (p4 & 2) ? e3 : t0;
}

// MODE 0: hist readout (separate kernel). MODE 1: in-kernel readout fallback.
template<int MODE>
__global__ __launch_bounds__(256, 1) void lstm_kernel(
    const float* __restrict__ x, const float* __restrict__ Wx,
    const float* __restrict__ bvec, const float* __restrict__ blp,
    const f16* __restrict__ wpack, f16* __restrict__ hbuf,
    const f16* __restrict__ wl16, f16* __restrict__ hhist,
    float* __restrict__ out)
{
    const int tid = threadIdx.x;
    const int cg = blockIdx.x >> 3;      // hidden-group 0..15 (32 units each)
    const int bg = blockIdx.x & 7;       // batch-group 0..7
    const int w = tid >> 6, lane = tid & 63;
    const int l_lo = lane & 15, l_hi = lane >> 4;

    __shared__ f16 hsh[2][8192];         // [row16][k512], XOR-swizzled, dbuf
    __shared__ f16 wlsh[512];

    if (tid < 64)                         // Wl -> LDS once (fallback readout)
        *(f16x8*)(wlsh + tid * 8) = *(const f16x8*)(wl16 + tid * 8);

    // ---- persistent B fragments: two 16-col tiles, slot s = jt=(w*4+s)&15 ----
    f16x8 bf0[16], bf1[16];
    {
        const f16x8* wp0 = (const f16x8*)wpack
                         + (size_t)(((cg * 4 + w) * 2 + 0) * 16) * 64 + lane;
        const f16x8* wp1 = (const f16x8*)wpack
                         + (size_t)(((cg * 4 + w) * 2 + 1) * 16) * 64 + lane;
#pragma unroll
        for (int s = 0; s < 16; ++s) { bf0[s] = wp0[s * 64]; bf1[s] = wp1[s * 64]; }
    }

    // ---- per-lane (row, unit) ownership after transpose ----
    const int row  = l_hi * 4 + (l_lo & 3);
    const int u0 = cg * 32 + w * 8 + (l_lo >> 2);      // tile0 unit
    const int u1 = u0 + 4;                             // tile1 unit
    const int bglob = bg * 16 + row;
    const float bi0 = bvec[0*512+u0], bfo0 = bvec[1*512+u0];
    const float bg0 = bvec[2*512+u0], bo0 = bvec[3*512+u0];
    const float bi1 = bvec[0*512+u1], bfo1 = bvec[1*512+u1];
    const float bg1 = bvec[2*512+u1], bo1 = bvec[3*512+u1];
    const float wxi0 = Wx[0*512+u0], wxf0 = Wx[1*512+u0];
    const float wxg0 = Wx[2*512+u0], wxo0 = Wx[3*512+u0];
    const float wxi1 = Wx[0*512+u1], wxf1 = Wx[1*512+u1];
    const float wxg1 = Wx[2*512+u1], wxo1 = Wx[3*512+u1];
    const float blv = blp[0];

    // poll: lane covers row l_lo, k in wave w's quarter (layout unchanged)
    const int rd_base = bg * 8192 + ((w * 16 + l_hi) * 16 + l_lo) * 8;
    // coalesced publish: wave owns kblock cg*4+w; writers l_lo<4, row l_hi*4+l_lo
    const int wrow = l_hi * 4 + l_lo;    // valid when l_lo < 4
    const int st_base = bg * 8192 + (cg * 4 + w) * 128 + wrow * 8;
    const size_t hist_base = (size_t)(bg * 16 + wrow) * HID + (cg * 4 + w) * 8;

    const int p4 = l_lo & 3;             // in-group transpose id
    const int sx = (l_lo & 7) << 4;      // LDS XOR swizzle
    const int lbase = l_lo * 1024;       // LDS row byte base
    const int base_ws = w * 256 + l_hi * 16;  // in-row byte off of slot 0
    const int xrow = bglob * TT;

    float cst0 = 0.f, cst1 = 0.f;
    const int TLAST = (MODE == 0) ? (TT - 1) : TT;

    for (int t = 0; t <= TLAST; ++t) {
        const f16* hp = hbuf + (size_t)(t & 3) * HBUF_ELEMS + rd_base;
        const unsigned ep = (unsigned)((t >> 2) & 1) * 0x00010001u;
        float xv = x[xrow + (t < TT ? t : 0)];   // hoisted; arrives under poll

        // ---- poll own quarter: all 32 tag bits (both halves) fresh ----
        f16x8 s0, s1, s2, s3;
        for (;;) {
            asm volatile(
                "global_load_dwordx4 %0, %4, off sc0 sc1\n\t"
                "global_load_dwordx4 %1, %5, off sc0 sc1\n\t"
                "global_load_dwordx4 %2, %6, off sc0 sc1\n\t"
                "global_load_dwordx4 %3, %7, off sc0 sc1\n\t"
                "s_waitcnt vmcnt(0)"
                : "=&v"(s0), "=&v"(s1), "=&v"(s2), "=&v"(s3)
                : "v"(hp), "v"(hp + 512), "v"(hp + 1024), "v"(hp + 1536)
                : "memory");
            union { f16x8 v; unsigned u[4]; } b0, b1, b2, b3;
            b0.v = s0; b1.v = s1; b2.v = s2; b3.v = s3;
            unsigned bad =
                (((b0.u[0]^ep)|(b0.u[1]^ep)|(b0.u[2]^ep)|(b0.u[3]^ep)) |
                 ((b1.u[0]^ep)|(b1.u[1]^ep)|(b1.u[2]^ep)|(b1.u[3]^ep)) |
                 ((b2.u[0]^ep)|(b2.u[1]^ep)|(b2.u[2]^ep)|(b2.u[3]^ep)) |
                 ((b3.u[0]^ep)|(b3.u[1]^ep)|(b3.u[2]^ep)|(b3.u[3]^ep))) & 0x00010001u;
            if (__all(bad == 0u)) break;
        }
        __builtin_amdgcn_sched_barrier(0);

        // ---- stage wave's k-quarter into shared h tile (swizzled) ----
        char* hb = (char*)hsh[t & 1];
        const int wb = lbase + base_ws;
        *(f16x8*)(hb + ((wb +   0) ^ sx)) = s0;
        *(f16x8*)(hb + ((wb +  64) ^ sx)) = s1;
        *(f16x8*)(hb + ((wb + 128) ^ sx)) = s2;
        *(f16x8*)(hb + ((wb + 192) ^ sx)) = s3;

        // ---- own-quarter MFMA chains BEFORE the barrier (both tiles) ----
        f32x4 cA0 = {0,0,0,0}, cA1 = {0,0,0,0};
        if (t < TT) {
            cA0 = __builtin_amdgcn_mfma_f32_16x16x32_f16(s0, bf0[0], cA0, 0,0,0);
            cA1 = __builtin_amdgcn_mfma_f32_16x16x32_f16(s0, bf1[0], cA1, 0,0,0);
            cA0 = __builtin_amdgcn_mfma_f32_16x16x32_f16(s1, bf0[1], cA0, 0,0,0);
            cA1 = __builtin_amdgcn_mfma_f32_16x16x32_f16(s1, bf1[1], cA1, 0,0,0);
            cA0 = __builtin_amdgcn_mfma_f32_16x16x32_f16(s2, bf0[2], cA0, 0,0,0);
            cA1 = __builtin_amdgcn_mfma_f32_16x16x32_f16(s2, bf1[2], cA1, 0,0,0);
            cA0 = __builtin_amdgcn_mfma_f32_16x16x32_f16(s3, bf0[3], cA0, 0,0,0);
            cA1 = __builtin_amdgcn_mfma_f32_16x16x32_f16(s3, bf1[3], cA1, 0,0,0);
        }
        __syncthreads();

        if (t < TT) {
            // ---- remaining 12 slots from LDS (read once, 2 MFMAs each) ----
            f32x4 cB0 = {0,0,0,0}, cB1 = {0,0,0,0};
            f32x4 cC0 = {0,0,0,0}, cC1 = {0,0,0,0};
            f32x4 cD0 = {0,0,0,0}, cD1 = {0,0,0,0};
#pragma unroll
            for (int i = 0; i < 4; ++i) {
                f16x8 a1 = *(const f16x8*)(hb + ((lbase + ((base_ws + (4+i)*64) & 1023)) ^ sx));
                f16x8 a2 = *(const f16x8*)(hb + ((lbase + ((base_ws + (8+i)*64) & 1023)) ^ sx));
                f16x8 a3 = *(const f16x8*)(hb + ((lbase + ((base_ws + (12+i)*64) & 1023)) ^ sx));
                cB0 = __builtin_amdgcn_mfma_f32_16x16x32_f16(a1, bf0[ 4+i], cB0, 0,0,0);
                cB1 = __builtin_amdgcn_mfma_f32_16x16x32_f16(a1, bf1[ 4+i], cB1, 0,0,0);
                cC0 = __builtin_amdgcn_mfma_f32_16x16x32_f16(a2, bf0[ 8+i], cC0, 0,0,0);
                cC1 = __builtin_amdgcn_mfma_f32_16x16x32_f16(a2, bf1[ 8+i], cC1, 0,0,0);
                cD0 = __builtin_amdgcn_mfma_f32_16x16x32_f16(a3, bf0[12+i], cD0, 0,0,0);
                cD1 = __builtin_amdgcn_mfma_f32_16x16x32_f16(a3, bf1[12+i], cD1, 0,0,0);
            }
            f32x4 m0 = (cA0 + cB0) + (cC0 + cD0);
            f32x4 m1 = (cA1 + cB1) + (cC1 + cD1);

            // ---- transpose + activations, two independent chains (ILP) ----
            float gi0, gf0, gg0, go0, gi1, gf1, gg1, go1;
            quad_transpose(m0, p4, gi0, gf0, gg0, go0);
            quad_transpose(m1, p4, gi1, gf1, gg1, go1);

            gi0 += xv * wxi0 + bi0;  gf0 += xv * wxf0 + bfo0;
            gg0 += xv * wxg0 + bg0;  go0 += xv * wxo0 + bo0;
            gi1 += xv * wxi1 + bi1;  gf1 += xv * wxf1 + bfo1;
            gg1 += xv * wxg1 + bg1;  go1 += xv * wxo1 + bo1;

            float iv0 = 1.f / (1.f + __expf(-gi0));
            float fv0 = 1.f / (1.f + __expf(-gf0));
            float gv0 = 2.f / (1.f + __expf(-2.f * gg0)) - 1.f;
            float ov0 = 1.f / (1.f + __expf(-go0));
            float iv1 = 1.f / (1.f + __expf(-gi1));
            float fv1 = 1.f / (1.f + __expf(-gf1));
            float gv1 = 2.f / (1.f + __expf(-2.f * gg1)) - 1.f;
            float ov1 = 1.f / (1.f + __expf(-go1));
            cst0 = fv0 * cst0 + iv0 * gv0;
            cst1 = fv1 * cst1 + iv1 * gv1;
            float hv0 = ov0 * (2.f / (1.f + __expf(-2.f * cst0)) - 1.f);
            float hv1 = ov1 * (2.f / (1.f + __expf(-2.f * cst1)) - 1.f);

            unsigned h0, h1;
            { union { f16 f; unsigned short s; } cv;
              cv.f = (f16)hv0; h0 = cv.s; cv.f = (f16)hv1; h1 = cv.s; }

            // ---- pack + gather: 1 dword/lane, 3 shfl_xor -> 4 dwords/row ----
            const unsigned wtag = (unsigned)(((t + 1) >> 2) & 1);
            unsigned p = ((h0 & 0xFFFEu) | wtag) | ((((h1 & 0xFFFEu) | wtag)) << 16);
            unsigned q1 = (unsigned)__shfl_xor((int)p, 4);
            unsigned q2 = (unsigned)__shfl_xor((int)p, 8);
            unsigned q3 = (unsigned)__shfl_xor((int)q1, 8);
            union { unsigned u[4]; f16x8 v; } pk;
            pk.u[0] = p; pk.u[1] = q1; pk.u[2] = q2; pk.u[3] = q3;

            if (l_lo < 4) {
                // exchange publish: ONE coalesced 256B burst per wave
                if ((MODE == 0) ? (t < TT - 1) : true) {
                    f16* dst = hbuf + (size_t)((t + 1) & 3) * HBUF_ELEMS + st_base;
                    asm volatile("global_store_dwordx4 %0, %1, off sc0 sc1"
                                 :: "v"(dst), "v"(pk.v) : "memory");
                }
                // hist side-store (same packed regs; tag bit = <=1ulp noise)
                if (MODE == 0) {
                    f16* hd = hhist + (size_t)t * (BATCH * HID) + hist_base;
                    asm volatile("global_store_dwordx4 %0, %1, off"
                                 :: "v"(hd), "v"(pk.v) : "memory");
                }
            }
        }

        // ---- fallback in-kernel readout, rotates over (cg,w) ----
        if (MODE == 1 && t >= 1 && cg == ((t >> 2) & 15) && w == (t & 3)) {
            float r0 = 0.f, r1 = 0.f, r2 = 0.f, r3 = 0.f;
#define WL(s) (*(const f16x8*)(wlsh + (((base_ws + (s)*64) & 1023) >> 1)))
            r0 = dot8(s0, WL(0), r0);
            r1 = dot8(s1, WL(1), r1);
            r2 = dot8(s2, WL(2), r2);
            r3 = dot8(s3, WL(3), r3);
#pragma unroll
            for (int i = 0; i < 4; ++i) {
                f16x8 a1 = *(const f16x8*)(hb + ((lbase + ((base_ws + (4+i)*64) & 1023)) ^ sx));
                f16x8 a2 = *(const f16x8*)(hb + ((lbase + ((base_ws + (8+i)*64) & 1023)) ^ sx));
                f16x8 a3 = *(const f16x8*)(hb + ((lbase + ((base_ws + (12+i)*64) & 1023)) ^ sx));
                r0 = dot8(a1, WL(4+i),  r0);
                r1 = dot8(a2, WL(8+i),  r1);
                r2 = dot8(a3, WL(12+i), r2);
            }
#undef WL
            float ry = (r0 + r1) + (r2 + r3);
            ry += __shfl_xor(ry, 16);
            ry += __shfl_xor(ry, 32);
            if (lane < 16)
                out[(bg * 16 + l_lo) * TT + (t - 1)] = blv + ry;
        }
    }
}

// y[b][t] = sum_u hhist[t][b][u_mem] * wlp[u_mem] + bl (both perm'd the same).
__global__ __launch_bounds__(256) void readout_kernel(
    const f16* __restrict__ hhist, const float* __restrict__ wlp,
    const float* __restrict__ blp, float* __restrict__ out)
{
    int gw = (blockIdx.x * 256 + threadIdx.x) >> 6;   // 0..16383
    int lane = threadIdx.x & 63;
    int b = gw >> 7;
    int t0 = (gw & 127) * 8;
    const float4* wp = (const float4*)(wlp + lane * 8);
    float4 wa = wp[0], wb = wp[1];
    float blv = blp[0];
    const f16* hp = hhist + (size_t)t0 * (BATCH * HID) + b * HID + lane * 8;
#pragma unroll
    for (int j = 0; j < 8; ++j) {
        f16x8 h8 = *(const f16x8*)(hp + (size_t)j * (BATCH * HID));
        float p = (float)h8[0]*wa.x + (float)h8[1]*wa.y + (float)h8[2]*wa.z +
                  (float)h8[3]*wa.w + (float)h8[4]*wb.x + (float)h8[5]*wb.y +
                  (float)h8[6]*wb.z + (float)h8[7]*wb.w;
        p += __shfl_xor(p, 1);  p += __shfl_xor(p, 2);  p += __shfl_xor(p, 4);
        p += __shfl_xor(p, 8);  p += __shfl_xor(p, 16); p += __shfl_xor(p, 32);
        if (lane == 0) out[b * TT + t0 + j] = p + blv;
    }
}

extern "C" void kernel_launch(void* const* d_in, const int* in_sizes, int n_in,
                              void* d_out, int out_size, void* d_ws, size_t ws_size,
                              hipStream_t stream) {
    const float* x  = (const float*)d_in[0];
    const float* Wx = (const float*)d_in[1];
    const float* Wh = (const float*)d_in[2];
    const float* bv = (const float*)d_in[3];
    const float* Wl = (const float*)d_in[4];
    const float* bl = (const float*)d_in[5];
    float* out = (float*)d_out;
    char* ws = (char*)d_ws;

    f16* wpack  = (f16*)(ws + WPACK_OFF);
    f16* hbuf   = (f16*)(ws + HBUF_OFF);
    f16* wl16   = (f16*)(ws + WL16_OFF);
    float* wlp  = (float*)(ws + WLP_OFF);
    f16* hhist  = (f16*)(ws + HHIST_OFF);

    init_kernel<<<512, 256, 0, stream>>>(Wl, wl16, wlp, (unsigned*)hbuf);
    pack_kernel<<<512, 256, 0, stream>>>(Wh, wpack);
    if (ws_size >= WS_NEEDED) {
        lstm_kernel<0><<<128, 256, 0, stream>>>(x, Wx, bv, bl, wpack, hbuf,
                                                wl16, hhist, out);
        readout_kernel<<<4096, 256, 0, stream>>>(hhist, wlp, bl, out);
    } else {
        lstm_kernel<1><<<128, 256, 0, stream>>>(x, Wx, bv, bl, wpack, hbuf,
                                                wl16, hhist, out);
    }
}

// Round 17
// 1792.664 us; speedup vs baseline: 1.3467x; 1.0008x over previous
//
#include <hip/hip_runtime.h>
#include <hip/hip_fp16.h>

// LSTM: B=128, T=1024, I=1, H=512, O=1
// R17 = R14 EXACT REVERT (proven best: 1.794 ms, passed).
// R15/R16 (piecewise poll, placement-verified XCD exchange) both deadlocked:
// the XCD-local family is unimplementable safely (3 distinct coherence
// hazards: warmup-poisoned fallback, stale-clean-line re-read, dual-dirty-
// line eviction race). This is the stable protocol: tag-in-payload LLC
// exchange, 4 rotating buffers, coalesced 256B publish, DPP transpose,
// hist side-store + separate readout kernel.

typedef _Float16 f16;
typedef _Float16 f16x8 __attribute__((ext_vector_type(8)));
typedef float f32x4 __attribute__((ext_vector_type(4)));

#define BATCH 128
#define TT 1024
#define HID 512

#define WPACK_OFF   0
#define WPACK_BYTES (16*4*2*16*64*16)            // 2 MiB packed f16 Wh fragments
#define HBUF_OFF    WPACK_BYTES
#define HBUF_ELEMS  (BATCH*HID)                  // 65536 f16 = 128 KiB per buffer
#define WL16_OFF    (HBUF_OFF + 4*HBUF_ELEMS*2)
#define WLP_OFF     (WL16_OFF + 1024)            // permuted float Wl (2 KB)
#define HHIST_OFF   (WL16_OFF + 4096)
#define HHIST_BYTES ((size_t)TT * BATCH * HID * 2)   // 128 MiB
#define WS_NEEDED   ((size_t)HHIST_OFF + HHIST_BYTES)

__device__ __host__ __forceinline__ int kperm(int e) {
    return (e >> 1) | ((e & 1) << 2);            // [0,4,1,5,2,6,3,7]
}

__global__ __launch_bounds__(256) void init_kernel(const float* Wl, f16* wl16,
                                                   float* wlp, unsigned* hbuf) {
    int idx = blockIdx.x * 256 + threadIdx.x;    // grid 512*256 = 131072
    // buf0 = zeros (h_0, tag 0); bufs 1..3 = 0x00010001 (both halves stale)
    hbuf[idx] = ((idx >> 15) == 0) ? 0u : 0x00010001u;
    if (idx < HID) {                             // permuted Wl copies
        int kb = idx >> 3, e = idx & 7;
        float v = Wl[kb * 8 + kperm(e)];
        wl16[idx] = (f16)v;
        wlp[idx] = v;
    }
}

// Pack Wh (512 x 2048, row = source k, col = gate*512 + j) into per-(cg,wv,T)
// B-fragments. Wave wv of cg owns units cg*32 + wv*8 .. +8; tile T covers
// units cg*32 + wv*8 + T*4 + jj. Slot s = physical k-tile jt=(wv*4+s)&15.
// k rows inside each kblock are permuted by kperm (matches publish layout).
__global__ __launch_bounds__(256) void pack_kernel(const float* __restrict__ Wh,
                                                   f16* __restrict__ wpack) {
    int tid  = blockIdx.x * 256 + threadIdx.x;   // 131072 = 16cg*4wv*2T*16s*64l
    int lane = tid & 63;
    int s    = (tid >> 6) & 15;
    int T    = (tid >> 10) & 1;
    int wv   = (tid >> 11) & 3;
    int cg   = tid >> 13;                        // 0..15
    int l_lo = lane & 15, l_hi = lane >> 4;
    int jt = ((wv * 4) + s) & 15;                // physical k-tile
    int jj = l_lo >> 2, q = l_lo & 3;
    int c = q * 512 + cg * 32 + wv * 8 + T * 4 + jj;
    int kbase = jt * 32 + l_hi * 8;
    f16x8 v;
#pragma unroll
    for (int e = 0; e < 8; ++e) v[e] = (f16)Wh[(kbase + kperm(e)) * 2048 + c];
    ((f16x8*)wpack)[tid] = v;
}

__device__ __forceinline__ float dot8(f16x8 a, f16x8 b, float acc) {
#if __has_builtin(__builtin_amdgcn_fdot2)
    acc = __builtin_amdgcn_fdot2(__builtin_shufflevector(a, a, 0, 1),
                                 __builtin_shufflevector(b, b, 0, 1), acc, false);
    acc = __builtin_amdgcn_fdot2(__builtin_shufflevector(a, a, 2, 3),
                                 __builtin_shufflevector(b, b, 2, 3), acc, false);
    acc = __builtin_amdgcn_fdot2(__builtin_shufflevector(a, a, 4, 5),
                                 __builtin_shufflevector(b, b, 4, 5), acc, false);
    acc = __builtin_amdgcn_fdot2(__builtin_shufflevector(a, a, 6, 7),
                                 __builtin_shufflevector(b, b, 6, 7), acc, false);
#else
#pragma unroll
    for (int e = 0; e < 8; ++e) acc += (float)a[e] * (float)b[e];
#endif
    return acc;
}

// quad_perm DPP: xor1 = 0xB1, xor2 = 0x4E (quad-local strides 1/2).
template<int CTRL>
__device__ __forceinline__ float dpp_qp(float v) {
    int r = __builtin_amdgcn_update_dpp(0, __builtin_bit_cast(int, v),
                                        CTRL, 0xF, 0xF, true);
    return __builtin_bit_cast(float, r);
}

// 4x4 transpose within aligned lane quads: m[0..3] -> (f0..f3) per p4.
__device__ __forceinline__ void quad_transpose(const f32x4& m, int p4,
                                               float& f0, float& f1,
                                               float& f2, float& f3) {
    float t0, e0, e1, e2, e3;
    t0 = dpp_qp<0xB1>(m[1]); e0 = (p4 & 1) ? t0 : m[0];
    t0 = dpp_qp<0xB1>(m[0]); e1 = (p4 & 1) ? m[1] : t0;
    t0 = dpp_qp<0xB1>(m[3]); e2 = (p4 & 1) ? t0 : m[2];
    t0 = dpp_qp<0xB1>(m[2]); e3 = (p4 & 1) ? m[3] : t0;
    t0 = dpp_qp<0x4E>(e2); f0 = (p4 & 2) ? t0 : e0;
    t0 = dpp_qp<0x4E>(e3); f1 = (p4 & 2) ? t0 : e1;
    t0 = dpp_qp<0x4E>(e0); f2 = (p4 & 2) ? e2 : t0;
    t0 = dpp_qp<0x4E>(e1); f3 = (p4 & 2) ? e3 : t0;
}

// MODE 0: hist readout (separate kernel). MODE 1: in-kernel readout fallback.
template<int MODE>
__global__ __launch_bounds__(256, 1) void lstm_kernel(
    const float* __restrict__ x, const float* __restrict__ Wx,
    const float* __restrict__ bvec, const float* __restrict__ blp,
    const f16* __restrict__ wpack, f16* __restrict__ hbuf,
    const f16* __restrict__ wl16, f16* __restrict__ hhist,
    float* __restrict__ out)
{
    const int tid = threadIdx.x;
    const int cg = blockIdx.x >> 3;      // hidden-group 0..15 (32 units each)
    const int bg = blockIdx.x & 7;       // batch-group 0..7
    const int w = tid >> 6, lane = tid & 63;
    const int l_lo = lane & 15, l_hi = lane >> 4;

    __shared__ f16 hsh[2][8192];         // [row16][k512], XOR-swizzled, dbuf
    __shared__ f16 wlsh[512];

    if (tid < 64)                         // Wl -> LDS once (fallback readout)
        *(f16x8*)(wlsh + tid * 8) = *(const f16x8*)(wl16 + tid * 8);

    // ---- persistent B fragments: two 16-col tiles, slot s = jt=(w*4+s)&15 ----
    f16x8 bf0[16], bf1[16];
    {
        const f16x8* wp0 = (const f16x8*)wpack
                         + (size_t)(((cg * 4 + w) * 2 + 0) * 16) * 64 + lane;
        const f16x8* wp1 = (const f16x8*)wpack
                         + (size_t)(((cg * 4 + w) * 2 + 1) * 16) * 64 + lane;
#pragma unroll
        for (int s = 0; s < 16; ++s) { bf0[s] = wp0[s * 64]; bf1[s] = wp1[s * 64]; }
    }

    // ---- per-lane (row, unit) ownership after transpose ----
    const int row  = l_hi * 4 + (l_lo & 3);
    const int u0 = cg * 32 + w * 8 + (l_lo >> 2);      // tile0 unit
    const int u1 = u0 + 4;                             // tile1 unit
    const int bglob = bg * 16 + row;
    const float bi0 = bvec[0*512+u0], bfo0 = bvec[1*512+u0];
    const float bg0 = bvec[2*512+u0], bo0 = bvec[3*512+u0];
    const float bi1 = bvec[0*512+u1], bfo1 = bvec[1*512+u1];
    const float bg1 = bvec[2*512+u1], bo1 = bvec[3*512+u1];
    const float wxi0 = Wx[0*512+u0], wxf0 = Wx[1*512+u0];
    const float wxg0 = Wx[2*512+u0], wxo0 = Wx[3*512+u0];
    const float wxi1 = Wx[0*512+u1], wxf1 = Wx[1*512+u1];
    const float wxg1 = Wx[2*512+u1], wxo1 = Wx[3*512+u1];
    const float blv = blp[0];

    // poll: lane covers row l_lo, k in wave w's quarter (layout unchanged)
    const int rd_base = bg * 8192 + ((w * 16 + l_hi) * 16 + l_lo) * 8;
    // coalesced publish: wave owns kblock cg*4+w; writers l_lo<4, row l_hi*4+l_lo
    const int wrow = l_hi * 4 + l_lo;    // valid when l_lo < 4
    const int st_base = bg * 8192 + (cg * 4 + w) * 128 + wrow * 8;
    const size_t hist_base = (size_t)(bg * 16 + wrow) * HID + (cg * 4 + w) * 8;

    const int p4 = l_lo & 3;             // in-group transpose id
    const int sx = (l_lo & 7) << 4;      // LDS XOR swizzle
    const int lbase = l_lo * 1024;       // LDS row byte base
    const int base_ws = w * 256 + l_hi * 16;  // in-row byte off of slot 0
    const int xrow = bglob * TT;

    float cst0 = 0.f, cst1 = 0.f;
    const int TLAST = (MODE == 0) ? (TT - 1) : TT;

    for (int t = 0; t <= TLAST; ++t) {
        const f16* hp = hbuf + (size_t)(t & 3) * HBUF_ELEMS + rd_base;
        const unsigned ep = (unsigned)((t >> 2) & 1) * 0x00010001u;
        float xv = x[xrow + (t < TT ? t : 0)];   // hoisted; arrives under poll

        // ---- poll own quarter: all 32 tag bits (both halves) fresh ----
        f16x8 s0, s1, s2, s3;
        for (;;) {
            asm volatile(
                "global_load_dwordx4 %0, %4, off sc0 sc1\n\t"
                "global_load_dwordx4 %1, %5, off sc0 sc1\n\t"
                "global_load_dwordx4 %2, %6, off sc0 sc1\n\t"
                "global_load_dwordx4 %3, %7, off sc0 sc1\n\t"
                "s_waitcnt vmcnt(0)"
                : "=&v"(s0), "=&v"(s1), "=&v"(s2), "=&v"(s3)
                : "v"(hp), "v"(hp + 512), "v"(hp + 1024), "v"(hp + 1536)
                : "memory");
            union { f16x8 v; unsigned u[4]; } b0, b1, b2, b3;
            b0.v = s0; b1.v = s1; b2.v = s2; b3.v = s3;
            unsigned bad =
                (((b0.u[0]^ep)|(b0.u[1]^ep)|(b0.u[2]^ep)|(b0.u[3]^ep)) |
                 ((b1.u[0]^ep)|(b1.u[1]^ep)|(b1.u[2]^ep)|(b1.u[3]^ep)) |
                 ((b2.u[0]^ep)|(b2.u[1]^ep)|(b2.u[2]^ep)|(b2.u[3]^ep)) |
                 ((b3.u[0]^ep)|(b3.u[1]^ep)|(b3.u[2]^ep)|(b3.u[3]^ep))) & 0x00010001u;
            if (__all(bad == 0u)) break;
        }
        __builtin_amdgcn_sched_barrier(0);

        // ---- stage wave's k-quarter into shared h tile (swizzled) ----
        char* hb = (char*)hsh[t & 1];
        const int wb = lbase + base_ws;
        *(f16x8*)(hb + ((wb +   0) ^ sx)) = s0;
        *(f16x8*)(hb + ((wb +  64) ^ sx)) = s1;
        *(f16x8*)(hb + ((wb + 128) ^ sx)) = s2;
        *(f16x8*)(hb + ((wb + 192) ^ sx)) = s3;

        // ---- own-quarter MFMA chains BEFORE the barrier (both tiles) ----
        f32x4 cA0 = {0,0,0,0}, cA1 = {0,0,0,0};
        if (t < TT) {
            cA0 = __builtin_amdgcn_mfma_f32_16x16x32_f16(s0, bf0[0], cA0, 0,0,0);
            cA1 = __builtin_amdgcn_mfma_f32_16x16x32_f16(s0, bf1[0], cA1, 0,0,0);
            cA0 = __builtin_amdgcn_mfma_f32_16x16x32_f16(s1, bf0[1], cA0, 0,0,0);
            cA1 = __builtin_amdgcn_mfma_f32_16x16x32_f16(s1, bf1[1], cA1, 0,0,0);
            cA0 = __builtin_amdgcn_mfma_f32_16x16x32_f16(s2, bf0[2], cA0, 0,0,0);
            cA1 = __builtin_amdgcn_mfma_f32_16x16x32_f16(s2, bf1[2], cA1, 0,0,0);
            cA0 = __builtin_amdgcn_mfma_f32_16x16x32_f16(s3, bf0[3], cA0, 0,0,0);
            cA1 = __builtin_amdgcn_mfma_f32_16x16x32_f16(s3, bf1[3], cA1, 0,0,0);
        }
        __syncthreads();

        if (t < TT) {
            // ---- remaining 12 slots from LDS (read once, 2 MFMAs each) ----
            f32x4 cB0 = {0,0,0,0}, cB1 = {0,0,0,0};
            f32x4 cC0 = {0,0,0,0}, cC1 = {0,0,0,0};
            f32x4 cD0 = {0,0,0,0}, cD1 = {0,0,0,0};
#pragma unroll
            for (int i = 0; i < 4; ++i) {
                f16x8 a1 = *(const f16x8*)(hb + ((lbase + ((base_ws + (4+i)*64) & 1023)) ^ sx));
                f16x8 a2 = *(const f16x8*)(hb + ((lbase + ((base_ws + (8+i)*64) & 1023)) ^ sx));
                f16x8 a3 = *(const f16x8*)(hb + ((lbase + ((base_ws + (12+i)*64) & 1023)) ^ sx));
                cB0 = __builtin_amdgcn_mfma_f32_16x16x32_f16(a1, bf0[ 4+i], cB0, 0,0,0);
                cB1 = __builtin_amdgcn_mfma_f32_16x16x32_f16(a1, bf1[ 4+i], cB1, 0,0,0);
                cC0 = __builtin_amdgcn_mfma_f32_16x16x32_f16(a2, bf0[ 8+i], cC0, 0,0,0);
                cC1 = __builtin_amdgcn_mfma_f32_16x16x32_f16(a2, bf1[ 8+i], cC1, 0,0,0);
                cD0 = __builtin_amdgcn_mfma_f32_16x16x32_f16(a3, bf0[12+i], cD0, 0,0,0);
                cD1 = __builtin_amdgcn_mfma_f32_16x16x32_f16(a3, bf1[12+i], cD1, 0,0,0);
            }
            f32x4 m0 = (cA0 + cB0) + (cC0 + cD0);
            f32x4 m1 = (cA1 + cB1) + (cC1 + cD1);

            // ---- transpose + activations, two independent chains (ILP) ----
            float gi0, gf0, gg0, go0, gi1, gf1, gg1, go1;
            quad_transpose(m0, p4, gi0, gf0, gg0, go0);
            quad_transpose(m1, p4, gi1, gf1, gg1, go1);

            gi0 += xv * wxi0 + bi0;  gf0 += xv * wxf0 + bfo0;
            gg0 += xv * wxg0 + bg0;  go0 += xv * wxo0 + bo0;
            gi1 += xv * wxi1 + bi1;  gf1 += xv * wxf1 + bfo1;
            gg1 += xv * wxg1 + bg1;  go1 += xv * wxo1 + bo1;

            float iv0 = 1.f / (1.f + __expf(-gi0));
            float fv0 = 1.f / (1.f + __expf(-gf0));
            float gv0 = 2.f / (1.f + __expf(-2.f * gg0)) - 1.f;
            float ov0 = 1.f / (1.f + __expf(-go0));
            float iv1 = 1.f / (1.f + __expf(-gi1));
            float fv1 = 1.f / (1.f + __expf(-gf1));
            float gv1 = 2.f / (1.f + __expf(-2.f * gg1)) - 1.f;
            float ov1 = 1.f / (1.f + __expf(-go1));
            cst0 = fv0 * cst0 + iv0 * gv0;
            cst1 = fv1 * cst1 + iv1 * gv1;
            float hv0 = ov0 * (2.f / (1.f + __expf(-2.f * cst0)) - 1.f);
            float hv1 = ov1 * (2.f / (1.f + __expf(-2.f * cst1)) - 1.f);

            unsigned h0, h1;
            { union { f16 f; unsigned short s; } cv;
              cv.f = (f16)hv0; h0 = cv.s; cv.f = (f16)hv1; h1 = cv.s; }

            // ---- pack + gather: 1 dword/lane, 3 shfl_xor -> 4 dwords/row ----
            const unsigned wtag = (unsigned)(((t + 1) >> 2) & 1);
            unsigned p = ((h0 & 0xFFFEu) | wtag) | ((((h1 & 0xFFFEu) | wtag)) << 16);
            unsigned q1 = (unsigned)__shfl_xor((int)p, 4);
            unsigned q2 = (unsigned)__shfl_xor((int)p, 8);
            unsigned q3 = (unsigned)__shfl_xor((int)q1, 8);
            union { unsigned u[4]; f16x8 v; } pk;
            pk.u[0] = p; pk.u[1] = q1; pk.u[2] = q2; pk.u[3] = q3;

            if (l_lo < 4) {
                // exchange publish: ONE coalesced 256B burst per wave
                if ((MODE == 0) ? (t < TT - 1) : true) {
                    f16* dst = hbuf + (size_t)((t + 1) & 3) * HBUF_ELEMS + st_base;
                    asm volatile("global_store_dwordx4 %0, %1, off sc0 sc1"
                                 :: "v"(dst), "v"(pk.v) : "memory");
                }
                // hist side-store (same packed regs; tag bit = <=1ulp noise)
                if (MODE == 0) {
                    f16* hd = hhist + (size_t)t * (BATCH * HID) + hist_base;
                    asm volatile("global_store_dwordx4 %0, %1, off"
                                 :: "v"(hd), "v"(pk.v) : "memory");
                }
            }
        }

        // ---- fallback in-kernel readout, rotates over (cg,w) ----
        if (MODE == 1 && t >= 1 && cg == ((t >> 2) & 15) && w == (t & 3)) {
            float r0 = 0.f, r1 = 0.f, r2 = 0.f, r3 = 0.f;
#define WL(s) (*(const f16x8*)(wlsh + (((base_ws + (s)*64) & 1023) >> 1)))
            r0 = dot8(s0, WL(0), r0);
            r1 = dot8(s1, WL(1), r1);
            r2 = dot8(s2, WL(2), r2);
            r3 = dot8(s3, WL(3), r3);
#pragma unroll
            for (int i = 0; i < 4; ++i) {
                f16x8 a1 = *(const f16x8*)(hb + ((lbase + ((base_ws + (4+i)*64) & 1023)) ^ sx));
                f16x8 a2 = *(const f16x8*)(hb + ((lbase + ((base_ws + (8+i)*64) & 1023)) ^ sx));
                f16x8 a3 = *(const f16x8*)(hb + ((lbase + ((base_ws + (12+i)*64) & 1023)) ^ sx));
                r0 = dot8(a1, WL(4+i),  r0);
                r1 = dot8(a2, WL(8+i),  r1);
                r2 = dot8(a3, WL(12+i), r2);
            }
#undef WL
            float ry = (r0 + r1) + (r2 + r3);
            ry += __shfl_xor(ry, 16);
            ry += __shfl_xor(ry, 32);
            if (lane < 16)
                out[(bg * 16 + l_lo) * TT + (t - 1)] = blv + ry;
        }
    }
}

// y[b][t] = sum_u hhist[t][b][u_mem] * wlp[u_mem] + bl (both perm'd the same).
__global__ __launch_bounds__(256) void readout_kernel(
    const f16* __restrict__ hhist, const float* __restrict__ wlp,
    const float* __restrict__ blp, float* __restrict__ out)
{
    int gw = (blockIdx.x * 256 + threadIdx.x) >> 6;   // 0..16383
    int lane = threadIdx.x & 63;
    int b = gw >> 7;
    int t0 = (gw & 127) * 8;
    const float4* wp = (const float4*)(wlp + lane * 8);
    float4 wa = wp[0], wb = wp[1];
    float blv = blp[0];
    const f16* hp = hhist + (size_t)t0 * (BATCH * HID) + b * HID + lane * 8;
#pragma unroll
    for (int j = 0; j < 8; ++j) {
        f16x8 h8 = *(const f16x8*)(hp + (size_t)j * (BATCH * HID));
        float p = (float)h8[0]*wa.x + (float)h8[1]*wa.y + (float)h8[2]*wa.z +
                  (float)h8[3]*wa.w + (float)h8[4]*wb.x + (float)h8[5]*wb.y +
                  (float)h8[6]*wb.z + (float)h8[7]*wb.w;
        p += __shfl_xor(p, 1);  p += __shfl_xor(p, 2);  p += __shfl_xor(p, 4);
        p += __shfl_xor(p, 8);  p += __shfl_xor(p, 16); p += __shfl_xor(p, 32);
        if (lane == 0) out[b * TT + t0 + j] = p + blv;
    }
}

extern "C" void kernel_launch(void* const* d_in, const int* in_sizes, int n_in,
                              void* d_out, int out_size, void* d_ws, size_t ws_size,
                              hipStream_t stream) {
    const float* x  = (const float*)d_in[0];
    const float* Wx = (const float*)d_in[1];
    const float* Wh = (const float*)d_in[2];
    const float* bv = (const float*)d_in[3];
    const float* Wl = (const float*)d_in[4];
    const float* bl = (const float*)d_in[5];
    float* out = (float*)d_out;
    char* ws = (char*)d_ws;

    f16* wpack  = (f16*)(ws + WPACK_OFF);
    f16* hbuf   = (f16*)(ws + HBUF_OFF);
    f16* wl16   = (f16*)(ws + WL16_OFF);
    float* wlp  = (float*)(ws + WLP_OFF);
    f16* hhist  = (f16*)(ws + HHIST_OFF);

    init_kernel<<<512, 256, 0, stream>>>(Wl, wl16, wlp, (unsigned*)hbuf);
    pack_kernel<<<512, 256, 0, stream>>>(Wh, wpack);
    if (ws_size >= WS_NEEDED) {
        lstm_kernel<0><<<128, 256, 0, stream>>>(x, Wx, bv, bl, wpack, hbuf,
                                                wl16, hhist, out);
        readout_kernel<<<4096, 256, 0, stream>>>(hhist, wlp, bl, out);
    } else {
        lstm_kernel<1><<<128, 256, 0, stream>>>(x, Wx, bv, bl, wpack, hbuf,
                                                wl16, hhist, out);
    }
}